// Round 5
// baseline (73.955 us; speedup 1.0000x reference)
//
#include <hip/hip_runtime.h>

// MaxChamferDistance: x[16,4096,3], y[16,4096,3] f32 -> scalar f32
//
// Round-5: round-4 was latency-stalled (real VALU issue ~32%, DS/barrier
// waits, ~1.7 eff waves/SIMD, 10us aux overhead). New structure:
//  - "Other"-cloud values are wave-uniform -> stream them via SCALAR loads
//    (s_load) into SGPRs. No LDS, no __syncthreads, no DS pipe at all.
//  - prep kernel transforms clouds once: q = (-2p, ||p||^2) float4 (2MB ws),
//    fused with pm init (atomicMin identity).
//  - main: 1024 blocks x 256 thr (16 waves/CU), POWN=4 own pts as 2x float2,
//    v_pk_fma_f32 inner: per 2 other-pts: ~18 insts / 16 pairs.
//  - cross-segment min via atomicMin on monotone-uint floats (order-indep,
//    replay-deterministic); finale = single block (sum/4096, max, mean).
//  - ws < 2.625MB fallback: PREP=false transforms other-points on the fly
//    (512KB pm only, budget proven in rounds 3-4).

#define BATCH   16
#define NPTS    4096
#define DB      (2 * BATCH)            // 32 (dir,batch) pairs
#define SEG     8
#define SEGPTS  (NPTS / SEG)           // 512
#define THREADS 256
#define POWN    4
#define CHUNK   (THREADS * POWN)       // 1024 own points per block
#define CHUNKS  (NPTS / CHUNK)         // 4
#define NB_MAIN (DB * SEG * CHUNKS)    // 1024 blocks
#define PM_U32  (DB * NPTS)            // 131072 u32 = 512 KB
#define QB_PTS  (DB * NPTS)            // 131072 float4 = 2 MB

typedef float v2f __attribute__((ext_vector_type(2)));

__device__ __forceinline__ v2f fma2(v2f a, v2f b, v2f c) {
  return __builtin_elementwise_fma(a, b, c);
}
__device__ __forceinline__ v2f splat2(float v) { return (v2f){v, v}; }

__device__ __forceinline__ unsigned enc_f32(float f) {
  unsigned u = __float_as_uint(f);
  return (u & 0x80000000u) ? ~u : (u | 0x80000000u);   // monotone in f
}
__device__ __forceinline__ float dec_f32(unsigned u) {
  return __uint_as_float((u & 0x80000000u) ? (u ^ 0x80000000u) : ~u);
}

// Fused: blocks [0,512) transform other-clouds into qbuf; [512,640) init pm.
__global__ __launch_bounds__(THREADS) void chamfer_prep(
    const float* __restrict__ x, const float* __restrict__ y,
    float4* __restrict__ qbuf, uint4* __restrict__ pm4) {
  const int bid = blockIdx.x;
  if (bid < 512) {
    const int idx = bid * THREADS + threadIdx.x;   // [0, 131072)
    const int db  = idx >> 12;                     // dir*16 + b
    const int m   = idx & (NPTS - 1);
    const int dir = db >> 4;
    const int b   = db & 15;
    const float* other = (dir == 0 ? y : x) + (size_t)b * NPTS * 3;
    float a0 = other[m * 3 + 0];
    float a1 = other[m * 3 + 1];
    float a2 = other[m * 3 + 2];
    qbuf[idx] = make_float4(-2.0f * a0, -2.0f * a1, -2.0f * a2,
                            fmaf(a2, a2, fmaf(a1, a1, a0 * a0)));
  } else {
    const int i = (bid - 512) * THREADS + threadIdx.x;   // [0, 32768)
    pm4[i] = make_uint4(0xFFFFFFFFu, 0xFFFFFFFFu, 0xFFFFFFFFu, 0xFFFFFFFFu);
  }
}

// pm-init only (small-ws fallback)
__global__ __launch_bounds__(THREADS) void chamfer_init(uint4* __restrict__ pm4) {
  const int i = blockIdx.x * THREADS + threadIdx.x;
  pm4[i] = make_uint4(0xFFFFFFFFu, 0xFFFFFFFFu, 0xFFFFFFFFu, 0xFFFFFFFFu);
}

template <bool PREP>
__global__ __launch_bounds__(THREADS) void chamfer_main(
    const float* __restrict__ x, const float* __restrict__ y,
    const float4* __restrict__ qbuf, unsigned* __restrict__ pm) {
  const int bid = blockIdx.x;
  const int db  = bid >> 5;            // 32 = SEG*CHUNKS blocks per db
  const int r   = bid & 31;
  const int s   = r >> 2;              // segment
  const int c   = r & 3;               // own chunk
  const int dir = db >> 4;
  const int b   = db & 15;

  const float* own = (dir == 0 ? x : y) + (size_t)b * NPTS * 3;

  // 4 own points as 2 packed float2 streams
  const int base = c * CHUNK + threadIdx.x;
  v2f x0[2], x1[2], x2[2], sq[2], mn[2];
  #pragma unroll
  for (int j = 0; j < 2; ++j) {
    const int pa = base + (2 * j) * THREADS;
    const int pb = pa + THREADS;
    float a0 = own[pa * 3 + 0], a1 = own[pa * 3 + 1], a2 = own[pa * 3 + 2];
    float b0 = own[pb * 3 + 0], b1 = own[pb * 3 + 1], b2 = own[pb * 3 + 2];
    x0[j] = (v2f){a0, b0};
    x1[j] = (v2f){a1, b1};
    x2[j] = (v2f){a2, b2};
    sq[j] = (v2f){fmaf(a2, a2, fmaf(a1, a1, a0 * a0)),
                  fmaf(b2, b2, fmaf(b1, b1, b0 * b0))};
    mn[j] = (v2f){1e30f, 1e30f};
  }

  if (PREP) {
    // wave-uniform stream -> scalar loads (SGPRs), no LDS, no barrier
    const float4* qs = qbuf + (size_t)db * NPTS + (size_t)s * SEGPTS;
    #pragma unroll 4
    for (int m = 0; m < SEGPTS; m += 2) {
      float4 q0 = qs[m];
      float4 q1 = qs[m + 1];
      #pragma unroll
      for (int j = 0; j < 2; ++j) {
        v2f t0 = fma2(x0[j], splat2(q0.x),
                 fma2(x1[j], splat2(q0.y),
                 fma2(x2[j], splat2(q0.z), splat2(q0.w))));
        v2f t1 = fma2(x0[j], splat2(q1.x),
                 fma2(x1[j], splat2(q1.y),
                 fma2(x2[j], splat2(q1.z), splat2(q1.w))));
        mn[j].x = fminf(fminf(t0.x, t1.x), mn[j].x);   // v_min3_f32
        mn[j].y = fminf(fminf(t0.y, t1.y), mn[j].y);
      }
    }
  } else {
    const float* other = (dir == 0 ? y : x) + (size_t)b * NPTS * 3;
    const float* rp = other + (size_t)s * SEGPTS * 3;
    #pragma unroll 4
    for (int m = 0; m < SEGPTS; m += 2) {
      float p0 = rp[m * 3 + 0], p1 = rp[m * 3 + 1], p2 = rp[m * 3 + 2];
      float r0 = rp[m * 3 + 3], r1 = rp[m * 3 + 4], r2 = rp[m * 3 + 5];
      float4 q0 = make_float4(-2.0f * p0, -2.0f * p1, -2.0f * p2,
                              fmaf(p2, p2, fmaf(p1, p1, p0 * p0)));
      float4 q1 = make_float4(-2.0f * r0, -2.0f * r1, -2.0f * r2,
                              fmaf(r2, r2, fmaf(r1, r1, r0 * r0)));
      #pragma unroll
      for (int j = 0; j < 2; ++j) {
        v2f t0 = fma2(x0[j], splat2(q0.x),
                 fma2(x1[j], splat2(q0.y),
                 fma2(x2[j], splat2(q0.z), splat2(q0.w))));
        v2f t1 = fma2(x0[j], splat2(q1.x),
                 fma2(x1[j], splat2(q1.y),
                 fma2(x2[j], splat2(q1.z), splat2(q1.w))));
        mn[j].x = fminf(fminf(t0.x, t1.x), mn[j].x);
        mn[j].y = fminf(fminf(t0.y, t1.y), mn[j].y);
      }
    }
  }

  unsigned* dst = pm + (size_t)db * NPTS;
  #pragma unroll
  for (int j = 0; j < 2; ++j) {
    const int pa = base + (2 * j) * THREADS;
    atomicMin(&dst[pa],           enc_f32(sq[j].x + mn[j].x));
    atomicMin(&dst[pa + THREADS], enc_f32(sq[j].y + mn[j].y));
  }
}

// Single block: per-db mean of mins, per-batch max of directions, batch mean.
__global__ __launch_bounds__(1024) void chamfer_finale(
    const unsigned* __restrict__ pm, float* __restrict__ out) {
  __shared__ float dls[DB];
  const int t   = threadIdx.x;
  const int db  = t >> 5;
  const int sub = t & 31;
  const uint4* q = (const uint4*)(pm + (size_t)db * NPTS + sub * 128);
  float s = 0.0f;
  #pragma unroll
  for (int i = 0; i < 32; ++i) {
    uint4 v = q[i];
    s += (dec_f32(v.x) + dec_f32(v.y)) + (dec_f32(v.z) + dec_f32(v.w));
  }
  #pragma unroll
  for (int off = 16; off > 0; off >>= 1) s += __shfl_down(s, off, 32);
  if (sub == 0) dls[db] = s * (1.0f / (float)NPTS);
  __syncthreads();
  if (t < BATCH) {
    float v = fmaxf(dls[t], dls[t + BATCH]);
    #pragma unroll
    for (int off = 8; off > 0; off >>= 1) v += __shfl_down(v, off, 16);
    if (t == 0) out[0] = v * (1.0f / (float)BATCH);
  }
}

extern "C" void kernel_launch(void* const* d_in, const int* in_sizes, int n_in,
                              void* d_out, int out_size, void* d_ws, size_t ws_size,
                              hipStream_t stream) {
  const float* x = (const float*)d_in[0];
  const float* y = (const float*)d_in[1];
  float* out = (float*)d_out;

  unsigned* pm = (unsigned*)d_ws;                               // 512 KB
  float4* qbuf = (float4*)((char*)d_ws + (size_t)PM_U32 * 4);   // 2 MB

  const size_t need_full = (size_t)PM_U32 * 4 + (size_t)QB_PTS * 16;
  if (ws_size >= need_full) {
    chamfer_prep<<<640, THREADS, 0, stream>>>(x, y, qbuf, (uint4*)pm);
    chamfer_main<true><<<NB_MAIN, THREADS, 0, stream>>>(x, y, qbuf, pm);
  } else {
    chamfer_init<<<PM_U32 / 4 / THREADS, THREADS, 0, stream>>>((uint4*)pm);
    chamfer_main<false><<<NB_MAIN, THREADS, 0, stream>>>(x, y, qbuf, pm);
  }
  chamfer_finale<<<1, 1024, 0, stream>>>(pm, out);
}

// Round 6
// 60.066 us; speedup vs baseline: 1.2312x; 1.2312x over previous
//
#include <hip/hip_runtime.h>

// MaxChamferDistance: x[16,4096,3], y[16,4096,3] f32 -> scalar f32
//
// Round-6: rounds 2-5 all pinned ~50us at 4 nominal waves/SIMD regardless of
// instruction mix (DS count /4: no change; no-LDS scalar stream: no change)
// => latency wall, not a pipe limit. Fix: 8 waves/SIMD.
//  - POWN=8 own pts/thread (4x v2f packed), __launch_bounds__(128,8) caps
//    VGPR at 64 => 16 blocks/CU x 2 waves = 8 waves/SIMD.
//  - grid 4096 blocks = 32 db x 4 own-chunks x 32 segments; SEGPTS=128,
//    SoA LDS 2KB (broadcast ds_read_b128, proven cheap rounds 3-4).
//  - inner: per 4 other-pts: 48 v_pk_fma_f32 + 16 v_min3_f32.
//  - aux slimmed: hipMemsetAsync inits pm (0xFF = enc identity) and cnt (0);
//    combine kernel folds the final max/mean via device-scope counter +
//    fences + agent-scope loads (fixed-order values => replay-deterministic).
// ws: pm 512KB | dist 32 f32 | cnt 1 u32.

#define BATCH   16
#define NPTS    4096
#define DB      (2 * BATCH)            // 32 (dir,batch) pairs
#define SEG     32
#define SEGPTS  (NPTS / SEG)           // 128
#define THREADS 128
#define POWN    8
#define PH      (POWN / 2)             // 4 packed groups
#define CHUNK   (THREADS * POWN)       // 1024 own points per block
#define CHUNKS  (NPTS / CHUNK)         // 4
#define NB_MAIN (SEG * DB * CHUNKS)    // 4096 blocks
#define PM_U32  (DB * NPTS)            // 131072 u32 = 512 KB

typedef float v2f __attribute__((ext_vector_type(2)));
typedef float v4f __attribute__((ext_vector_type(4)));

__device__ __forceinline__ v2f fma2(v2f a, v2f b, v2f c) {
  return __builtin_elementwise_fma(a, b, c);
}
__device__ __forceinline__ v2f splat2(float v) { return (v2f){v, v}; }

__device__ __forceinline__ unsigned enc_f32(float f) {
  unsigned u = __float_as_uint(f);
  return (u & 0x80000000u) ? ~u : (u | 0x80000000u);   // monotone in f
}
__device__ __forceinline__ float dec_f32(unsigned u) {
  return __uint_as_float((u & 0x80000000u) ? (u ^ 0x80000000u) : ~u);
}

__global__ __launch_bounds__(THREADS, 8) void chamfer_main(
    const float* __restrict__ x, const float* __restrict__ y,
    unsigned* __restrict__ pm) {
  __shared__ __align__(16) float lq[4][SEGPTS];  // SoA (-2p0,-2p1,-2p2,||p||^2)

  const int bid = blockIdx.x;
  const int s   = bid >> 7;            // segment (128 blocks each)
  const int rem = bid & 127;
  const int db  = rem >> 2;            // dir*16 + b
  const int c   = rem & 3;             // own-point chunk
  const int dir = db >> 4;
  const int b   = db & 15;

  const float* own   = (dir == 0 ? x : y) + (size_t)b * NPTS * 3;
  const float* other = (dir == 0 ? y : x) + (size_t)b * NPTS * 3;
  const float* sp    = other + (size_t)s * SEGPTS * 3;

  {
    const int i = threadIdx.x;         // THREADS == SEGPTS
    float a0 = sp[i * 3 + 0];
    float a1 = sp[i * 3 + 1];
    float a2 = sp[i * 3 + 2];
    lq[0][i] = -2.0f * a0;
    lq[1][i] = -2.0f * a1;
    lq[2][i] = -2.0f * a2;
    lq[3][i] = fmaf(a2, a2, fmaf(a1, a1, a0 * a0));
  }
  __syncthreads();

  // 8 own points as 4 packed float2 streams (sq recomputed at epilogue
  // to keep live VGPRs under the launch-bounds cap)
  const int base = c * CHUNK + threadIdx.x;
  v2f x0p[PH], x1p[PH], x2p[PH], mnp[PH];
  #pragma unroll
  for (int j = 0; j < PH; ++j) {
    const int pa = base + (2 * j) * THREADS;
    const int pb = pa + THREADS;
    x0p[j] = (v2f){own[pa * 3 + 0], own[pb * 3 + 0]};
    x1p[j] = (v2f){own[pa * 3 + 1], own[pb * 3 + 1]};
    x2p[j] = (v2f){own[pa * 3 + 2], own[pb * 3 + 2]};
    mnp[j] = (v2f){1e30f, 1e30f};
  }

  for (int m = 0; m < SEGPTS; m += 4) {
    v4f qx = *(const v4f*)&lq[0][m];   // broadcast ds_read_b128 (uniform addr)
    v4f qy = *(const v4f*)&lq[1][m];
    v4f qz = *(const v4f*)&lq[2][m];
    v4f qw = *(const v4f*)&lq[3][m];
    #pragma unroll
    for (int j = 0; j < PH; ++j) {
      v2f t0 = fma2(x0p[j], splat2(qx.x),
               fma2(x1p[j], splat2(qy.x),
               fma2(x2p[j], splat2(qz.x), splat2(qw.x))));
      v2f t1 = fma2(x0p[j], splat2(qx.y),
               fma2(x1p[j], splat2(qy.y),
               fma2(x2p[j], splat2(qz.y), splat2(qw.y))));
      v2f t2 = fma2(x0p[j], splat2(qx.z),
               fma2(x1p[j], splat2(qy.z),
               fma2(x2p[j], splat2(qz.z), splat2(qw.z))));
      v2f t3 = fma2(x0p[j], splat2(qx.w),
               fma2(x1p[j], splat2(qy.w),
               fma2(x2p[j], splat2(qz.w), splat2(qw.w))));
      // v_min3_f32-friendly nesting: 2 min3 per half
      float ux = fminf(fminf(t0.x, t1.x), t2.x);
      float uy = fminf(fminf(t0.y, t1.y), t2.y);
      mnp[j].x = fminf(fminf(ux, t3.x), mnp[j].x);
      mnp[j].y = fminf(fminf(uy, t3.y), mnp[j].y);
    }
  }

  unsigned* dst = pm + (size_t)db * NPTS;
  #pragma unroll
  for (int j = 0; j < PH; ++j) {
    v2f sq = fma2(x2p[j], x2p[j], fma2(x1p[j], x1p[j], x0p[j] * x0p[j]));
    const int pa = base + (2 * j) * THREADS;
    atomicMin(&dst[pa],           enc_f32(sq.x + mnp[j].x));
    atomicMin(&dst[pa + THREADS], enc_f32(sq.y + mnp[j].y));
  }
}

// 32 blocks: per-db mean-of-mins; last block folds max/mean -> out.
__global__ __launch_bounds__(256) void chamfer_combine(
    const unsigned* __restrict__ pm, float* __restrict__ dist,
    unsigned* __restrict__ cnt, float* __restrict__ out) {
  const int db = blockIdx.x;
  const unsigned* q = pm + (size_t)db * NPTS;
  float s = 0.0f;
  #pragma unroll
  for (int i = threadIdx.x; i < NPTS; i += 256)
    s += dec_f32(q[i]);
  #pragma unroll
  for (int off = 32; off > 0; off >>= 1) s += __shfl_down(s, off, 64);
  __shared__ float red[4];
  const int lane = threadIdx.x & 63, wid = threadIdx.x >> 6;
  if (lane == 0) red[wid] = s;
  __syncthreads();
  if (threadIdx.x == 0) {
    dist[db] = ((red[0] + red[1]) + (red[2] + red[3])) * (1.0f / (float)NPTS);
    __threadfence();                                   // release dist[db]
    unsigned old = __hip_atomic_fetch_add(cnt, 1u, __ATOMIC_ACQ_REL,
                                          __HIP_MEMORY_SCOPE_AGENT);
    if (old == DB - 1) {                               // last block: finale
      __threadfence();                                 // acquire side
      float dls[DB];
      #pragma unroll
      for (int i = 0; i < DB; ++i)
        dls[i] = __uint_as_float(__hip_atomic_load(
            (const unsigned*)&dist[i], __ATOMIC_RELAXED,
            __HIP_MEMORY_SCOPE_AGENT));
      float acc = 0.0f;
      #pragma unroll
      for (int b = 0; b < BATCH; ++b) acc += fmaxf(dls[b], dls[b + BATCH]);
      out[0] = acc * (1.0f / (float)BATCH);
    }
  }
}

extern "C" void kernel_launch(void* const* d_in, const int* in_sizes, int n_in,
                              void* d_out, int out_size, void* d_ws, size_t ws_size,
                              hipStream_t stream) {
  const float* x = (const float*)d_in[0];
  const float* y = (const float*)d_in[1];
  float* out = (float*)d_out;

  unsigned* pm  = (unsigned*)d_ws;                    // 512 KB
  float* dist   = (float*)(pm + PM_U32);              // 32 f32
  unsigned* cnt = (unsigned*)(dist + DB);             // 1 u32

  hipMemsetAsync(pm, 0xFF, (size_t)PM_U32 * 4, stream);   // enc(+inf) identity
  hipMemsetAsync(cnt, 0, 4, stream);
  chamfer_main<<<NB_MAIN, THREADS, 0, stream>>>(x, y, pm);
  chamfer_combine<<<DB, 256, 0, stream>>>(pm, dist, cnt, out);
}

// Round 7
// 53.059 us; speedup vs baseline: 1.3938x; 1.1321x over previous
//
#include <hip/hip_runtime.h>

// MaxChamferDistance: x[16,4096,3], y[16,4096,3] f32 -> scalar f32
//
// Round-7: rounds 2-6 pinned at ~46-50us main with real VALU ~15us (floor
// ~14us) regardless of DS-count/occupancy changes => per-wave stalls on the
// LDS broadcast stream + aux overhead. This round removes the DS pipe, the
// atomics, and the memset entirely:
//  - prep: transform both clouds once into qbuf = (-2p, ||p||^2) float4 (2MB).
//  - main: block = (db, 256 own pts); 16 waves; wave w streams its 256-pt
//    other-segment from qbuf via SCALAR loads (wave-uniform address from
//    readfirstlane(wave-id) => s_load_dwordx16, scalar pipe, issues parallel
//    to VALU). Inner: 3 v_pk_fma chain + min3 per 2 pairs (2 inst/pair).
//    Cross-wave min via 16KB LDS, block-local, fixed order; block sum ->
//    partials[512]. No atomics, no global pm, no memset. Deterministic.
//  - finale: 1 block folds 512 partials -> mean/max/mean -> out.
// ws: qbuf 2MB + partials 2KB (r5 proved ws >= 2.625MB).

#define BATCH   16
#define NPTS    4096
#define DB      (2 * BATCH)          // 32 (dir,batch) pairs
#define WAVES   16                   // waves per block = other-segments
#define TPB     (WAVES * 64)         // 1024 threads
#define SEGPTS  (NPTS / WAVES)       // 256 other pts per wave
#define CHUNK   256                  // own pts per block
#define CHUNKS  (NPTS / CHUNK)       // 16
#define NBLK    (DB * CHUNKS)        // 512 blocks
#define PH      2                    // 4 own pts/thread as 2 packed float2
#define QB_PTS  (DB * NPTS)          // 131072 float4 = 2 MB

typedef float v2f __attribute__((ext_vector_type(2)));

static __device__ __forceinline__ v2f fma2(v2f a, v2f b, v2f c) {
  return __builtin_elementwise_fma(a, b, c);
}
static __device__ __forceinline__ v2f splat2(float v) { return (v2f){v, v}; }

__global__ __launch_bounds__(512) void chamfer_prep(
    const float* __restrict__ x, const float* __restrict__ y,
    float4* __restrict__ qbuf) {
  const int idx = blockIdx.x * 512 + threadIdx.x;   // [0, 131072)
  const int db  = idx >> 12;
  const int m   = idx & (NPTS - 1);
  const int dir = db >> 4;
  const int b   = db & 15;
  const float* other = (dir == 0 ? y : x) + (size_t)b * NPTS * 3;
  float a0 = other[m * 3 + 0];
  float a1 = other[m * 3 + 1];
  float a2 = other[m * 3 + 2];
  qbuf[idx] = make_float4(-2.0f * a0, -2.0f * a1, -2.0f * a2,
                          fmaf(a2, a2, fmaf(a1, a1, a0 * a0)));
}

__global__ __launch_bounds__(TPB) void chamfer_main(
    const float* __restrict__ x, const float* __restrict__ y,
    const float4* __restrict__ qbuf, float* __restrict__ partials) {
  __shared__ float mins[WAVES][CHUNK];   // 16 KB

  const int bid  = blockIdx.x;
  const int db   = bid >> 4;            // 16 chunks per db
  const int c    = bid & 15;
  const int dir  = db >> 4;
  const int b    = db & 15;
  // readfirstlane marks the wave id uniform => qs is wave-uniform => s_load
  const int w    = __builtin_amdgcn_readfirstlane((int)(threadIdx.x >> 6));
  const int lane = threadIdx.x & 63;

  const float* own = (dir == 0 ? x : y) + (size_t)b * NPTS * 3;
  const float4* __restrict__ qs =
      qbuf + (size_t)db * NPTS + (size_t)w * SEGPTS;

  // 4 own points per thread as 2 packed float2 streams
  const int base = c * CHUNK + lane;
  v2f x0p[PH], x1p[PH], x2p[PH], mnp[PH];
  #pragma unroll
  for (int j = 0; j < PH; ++j) {
    const int pa = base + (2 * j) * 64;
    const int pb = pa + 64;
    x0p[j] = (v2f){own[pa * 3 + 0], own[pb * 3 + 0]};
    x1p[j] = (v2f){own[pa * 3 + 1], own[pb * 3 + 1]};
    x2p[j] = (v2f){own[pa * 3 + 2], own[pb * 3 + 2]};
    mnp[j] = (v2f){1e30f, 1e30f};
  }

  #pragma unroll 2
  for (int m = 0; m < SEGPTS; m += 4) {
    float4 q0 = qs[m + 0];             // wave-uniform -> s_load_dwordx16
    float4 q1 = qs[m + 1];
    float4 q2 = qs[m + 2];
    float4 q3 = qs[m + 3];
    #pragma unroll
    for (int j = 0; j < PH; ++j) {
      v2f t0 = fma2(x0p[j], splat2(q0.x),
               fma2(x1p[j], splat2(q0.y),
               fma2(x2p[j], splat2(q0.z), splat2(q0.w))));
      v2f t1 = fma2(x0p[j], splat2(q1.x),
               fma2(x1p[j], splat2(q1.y),
               fma2(x2p[j], splat2(q1.z), splat2(q1.w))));
      v2f t2 = fma2(x0p[j], splat2(q2.x),
               fma2(x1p[j], splat2(q2.y),
               fma2(x2p[j], splat2(q2.z), splat2(q2.w))));
      v2f t3 = fma2(x0p[j], splat2(q3.x),
               fma2(x1p[j], splat2(q3.y),
               fma2(x2p[j], splat2(q3.z), splat2(q3.w))));
      float ux = fminf(fminf(t0.x, t1.x), t2.x);      // v_min3_f32
      float uy = fminf(fminf(t0.y, t1.y), t2.y);
      mnp[j].x = fminf(fminf(ux, t3.x), mnp[j].x);
      mnp[j].y = fminf(fminf(uy, t3.y), mnp[j].y);
    }
  }

  // fold ||x||^2 in, publish per-wave mins (min is order-independent)
  #pragma unroll
  for (int j = 0; j < PH; ++j) {
    v2f sq = fma2(x2p[j], x2p[j], fma2(x1p[j], x1p[j], x0p[j] * x0p[j]));
    const int la = lane + (2 * j) * 64;
    mins[w][la]      = sq.x + mnp[j].x;
    mins[w][la + 64] = sq.y + mnp[j].y;
  }
  __syncthreads();

  // wave 0 only: cross-wave min (fixed order) + block sum (fixed order)
  if (threadIdx.x < 64) {
    float acc = 0.0f;
    #pragma unroll
    for (int k = 0; k < CHUNK / 64; ++k) {
      const int t = lane + k * 64;
      float v = mins[0][t];
      #pragma unroll
      for (int u = 1; u < WAVES; ++u) v = fminf(v, mins[u][t]);
      acc += v;
    }
    #pragma unroll
    for (int off = 32; off > 0; off >>= 1) acc += __shfl_down(acc, off, 64);
    if (lane == 0) partials[bid] = acc;
  }
}

// 1 block: per-db mean of mins, per-batch max of directions, batch mean.
__global__ __launch_bounds__(64) void chamfer_finale(
    const float* __restrict__ partials, float* __restrict__ out) {
  const int t = threadIdx.x;            // 64 threads
  float dls = 0.0f;
  if (t < DB) {
    #pragma unroll
    for (int k = 0; k < CHUNKS; ++k) dls += partials[t * CHUNKS + k];
    dls *= (1.0f / (float)NPTS);
  }
  float o  = __shfl(dls, t + BATCH, 64);     // dls of the other direction
  float mx = fmaxf(dls, o);                  // valid for t < 16
  #pragma unroll
  for (int off = 8; off > 0; off >>= 1) mx += __shfl_down(mx, off, 16);
  if (t == 0) out[0] = mx * (1.0f / (float)BATCH);
}

extern "C" void kernel_launch(void* const* d_in, const int* in_sizes, int n_in,
                              void* d_out, int out_size, void* d_ws, size_t ws_size,
                              hipStream_t stream) {
  const float* x = (const float*)d_in[0];
  const float* y = (const float*)d_in[1];
  float* out = (float*)d_out;

  float4* qbuf    = (float4*)d_ws;                    // 2 MB
  float* partials = (float*)(qbuf + QB_PTS);          // 512 f32

  chamfer_prep<<<QB_PTS / 512, 512, 0, stream>>>(x, y, qbuf);
  chamfer_main<<<NBLK, TPB, 0, stream>>>(x, y, qbuf, partials);
  chamfer_finale<<<1, 64, 0, stream>>>(partials, out);
}

// Round 8
// 52.919 us; speedup vs baseline: 1.3975x; 1.0026x over previous
//
#include <hip/hip_runtime.h>

// MaxChamferDistance: x[16,4096,3], y[16,4096,3] f32 -> scalar f32
//
// Round-8: VALU-pipe floor is ~24us (pk_fma does NOT double fp32 rate:
// 157TF peak = 1 FMA/lane/cy; pk occupies 4cy). Prior rounds each missed one
// of: in-order pipelinable stream / 8K waves / high FMA density. This round
// has all three:
//  - 1024 blocks x 512 thr (8 waves) = 8192 waves (nominal 32/CU).
//  - block = (db, own-chunk of 512, other-group of 1024). Other pts staged
//    SoA (-2p,||p||^2) in 16KB LDS; wave w streams its PRIVATE 128-pt slice
//    via ds_read_b128 (in-order, counted lgkmcnt => compiler pipelines;
//    unlike SMEM's all-or-nothing lgkmcnt(0) which serialized round 7).
//  - 8 own pts/thread (4x v2f): per 4 other-pts = 4 DS + 48 pk_fma + 16 min3
//    => VALU:DS pipe 224:48 cy, DS hidden.
//  - cross-wave min via LDS (padded, conflict-free); per-group min written
//    NON-atomically to group-major gm[4][32][4096] (2MB ws): no atomics, no
//    memset, 2 kernel nodes, deterministic.
//  - combine: 32 blocks min over 4 groups + sum; counter-fused finale
//    (r6-proven); cnt zeroed by main block 0 (stream-ordered before combine).

#define BATCH   16
#define NPTS    4096
#define DB      (2 * BATCH)          // 32 (dir,batch)
#define TPB     512                  // 8 waves
#define WPB     8
#define OWNC    512                  // own pts per block
#define PH      4                    // 8 own pts as 4 packed float2
#define OGROUPS 4
#define ORANGE  (NPTS / OGROUPS)     // 1024 other pts per block
#define WSEG    (ORANGE / WPB)       // 128 other pts per wave
#define OCHUNKS (NPTS / OWNC)        // 8
#define NBLK    (DB * OCHUNKS * OGROUPS)  // 1024
#define GM_F32  (OGROUPS * DB * NPTS)     // 524288 floats = 2 MB

typedef float v2f __attribute__((ext_vector_type(2)));

static __device__ __forceinline__ v2f fma2(v2f a, v2f b, v2f c) {
  return __builtin_elementwise_fma(a, b, c);
}
static __device__ __forceinline__ v2f splat2(float v) { return (v2f){v, v}; }

__global__ __launch_bounds__(TPB, 6) void chamfer_main(
    const float* __restrict__ x, const float* __restrict__ y,
    float* __restrict__ gm, unsigned* __restrict__ cnt) {
  __shared__ __align__(16) float lq[4][ORANGE];      // 16 KB SoA
  __shared__ float mins[WPB][OWNC / WPB * WPB / 8 * 8 + 0 + 516 - OWNC];  // see below
  // NOTE: mins is [WPB][516] = 16.5 KB (pad 4 to break bank alignment)
  // (expression above must equal 516; keep it literal instead:)

  const int bid = blockIdx.x;
  if (bid == 0 && threadIdx.x == 0) *cnt = 0;        // reset for combine pass

  const int db = bid >> 5;             // 32 = OCHUNKS*OGROUPS blocks per db
  const int r  = bid & 31;
  const int c  = r >> 2;               // own chunk
  const int g  = r & 3;                // other group
  const int dir = db >> 4;
  const int b   = db & 15;

  const float* own   = (dir == 0 ? x : y) + (size_t)b * NPTS * 3;
  const float* other = (dir == 0 ? y : x) + (size_t)b * NPTS * 3;
  const float* op    = other + (size_t)g * ORANGE * 3;

  // stage 1024 other pts, SoA, transformed: (-2p0,-2p1,-2p2,||p||^2)
  #pragma unroll
  for (int k = 0; k < 2; ++k) {
    const int i = threadIdx.x + k * TPB;             // [0,1024)
    float a0 = op[i * 3 + 0];
    float a1 = op[i * 3 + 1];
    float a2 = op[i * 3 + 2];
    lq[0][i] = -2.0f * a0;
    lq[1][i] = -2.0f * a1;
    lq[2][i] = -2.0f * a2;
    lq[3][i] = fmaf(a2, a2, fmaf(a1, a1, a0 * a0));
  }

  const int w    = __builtin_amdgcn_readfirstlane((int)(threadIdx.x >> 6));
  const int lane = threadIdx.x & 63;

  // 8 own points per lane as 4 packed float2 (same own pts for all waves)
  const int base = c * OWNC + lane;
  v2f x0p[PH], x1p[PH], x2p[PH], mnp[PH];
  #pragma unroll
  for (int j = 0; j < PH; ++j) {
    const int pa = base + (2 * j) * 64;
    const int pb = pa + 64;
    x0p[j] = (v2f){own[pa * 3 + 0], own[pb * 3 + 0]};
    x1p[j] = (v2f){own[pa * 3 + 1], own[pb * 3 + 1]};
    x2p[j] = (v2f){own[pa * 3 + 2], own[pb * 3 + 2]};
    mnp[j] = (v2f){1e30f, 1e30f};
  }
  __syncthreads();

  // stream this wave's private 128-pt slice from LDS (in-order ds_read_b128)
  const int mbase = w * WSEG;
  #pragma unroll 2
  for (int m = 0; m < WSEG; m += 4) {
    const float4 qx = *(const float4*)&lq[0][mbase + m];
    const float4 qy = *(const float4*)&lq[1][mbase + m];
    const float4 qz = *(const float4*)&lq[2][mbase + m];
    const float4 qw = *(const float4*)&lq[3][mbase + m];
    #pragma unroll
    for (int j = 0; j < PH; ++j) {
      v2f t0 = fma2(x0p[j], splat2(qx.x),
               fma2(x1p[j], splat2(qy.x),
               fma2(x2p[j], splat2(qz.x), splat2(qw.x))));
      v2f t1 = fma2(x0p[j], splat2(qx.y),
               fma2(x1p[j], splat2(qy.y),
               fma2(x2p[j], splat2(qz.y), splat2(qw.y))));
      v2f t2 = fma2(x0p[j], splat2(qx.z),
               fma2(x1p[j], splat2(qy.z),
               fma2(x2p[j], splat2(qz.z), splat2(qw.z))));
      v2f t3 = fma2(x0p[j], splat2(qx.w),
               fma2(x1p[j], splat2(qy.w),
               fma2(x2p[j], splat2(qz.w), splat2(qw.w))));
      float ux = fminf(fminf(t0.x, t1.x), t2.x);     // v_min3_f32
      float uy = fminf(fminf(t0.y, t1.y), t2.y);
      mnp[j].x = fminf(fminf(ux, t3.x), mnp[j].x);
      mnp[j].y = fminf(fminf(uy, t3.y), mnp[j].y);
    }
  }

  // fold ||x||^2, publish per-wave mins (pad 516 breaks bank alignment)
  float (*mm)[516] = (float (*)[516])&mins[0][0];
  #pragma unroll
  for (int j = 0; j < PH; ++j) {
    v2f sq = fma2(x2p[j], x2p[j], fma2(x1p[j], x1p[j], x0p[j] * x0p[j]));
    const int la = lane + (2 * j) * 64;
    mm[w][la]      = sq.x + mnp[j].x;
    mm[w][la + 64] = sq.y + mnp[j].y;
  }
  __syncthreads();

  // cross-wave min (fixed order) -> group-major slab, coalesced, no atomics
  {
    const int i = threadIdx.x;                       // [0,512)
    float v = mm[0][i];
    #pragma unroll
    for (int u = 1; u < WPB; ++u) v = fminf(v, mm[u][i]);
    gm[(size_t)g * (DB * NPTS) + (size_t)db * NPTS + c * OWNC + i] = v;
  }
}

// 32 blocks: min over 4 groups + per-db mean; last block folds max/mean.
__global__ __launch_bounds__(256) void chamfer_combine(
    const float* __restrict__ gm, float* __restrict__ dist,
    unsigned* __restrict__ cnt, float* __restrict__ out) {
  const int db = blockIdx.x;
  float s = 0.0f;
  for (int i = threadIdx.x; i < NPTS; i += 256) {
    const size_t o = (size_t)db * NPTS + i;
    float v0 = gm[o];
    float v1 = gm[o + (size_t)DB * NPTS];
    float v2 = gm[o + (size_t)2 * DB * NPTS];
    float v3 = gm[o + (size_t)3 * DB * NPTS];
    s += fminf(fminf(v0, v1), fminf(v2, v3));
  }
  #pragma unroll
  for (int off = 32; off > 0; off >>= 1) s += __shfl_down(s, off, 64);
  __shared__ float red[4];
  const int lane = threadIdx.x & 63, wid = threadIdx.x >> 6;
  if (lane == 0) red[wid] = s;
  __syncthreads();
  if (threadIdx.x == 0) {
    dist[db] = ((red[0] + red[1]) + (red[2] + red[3])) * (1.0f / (float)NPTS);
    __threadfence();
    unsigned old = __hip_atomic_fetch_add(cnt, 1u, __ATOMIC_ACQ_REL,
                                          __HIP_MEMORY_SCOPE_AGENT);
    if (old == DB - 1) {
      __threadfence();
      float acc = 0.0f;
      #pragma unroll
      for (int b = 0; b < BATCH; ++b) {
        float d0 = __uint_as_float(__hip_atomic_load(
            (const unsigned*)&dist[b], __ATOMIC_RELAXED,
            __HIP_MEMORY_SCOPE_AGENT));
        float d1 = __uint_as_float(__hip_atomic_load(
            (const unsigned*)&dist[b + BATCH], __ATOMIC_RELAXED,
            __HIP_MEMORY_SCOPE_AGENT));
        acc += fmaxf(d0, d1);
      }
      out[0] = acc * (1.0f / (float)BATCH);
    }
  }
}

extern "C" void kernel_launch(void* const* d_in, const int* in_sizes, int n_in,
                              void* d_out, int out_size, void* d_ws, size_t ws_size,
                              hipStream_t stream) {
  const float* x = (const float*)d_in[0];
  const float* y = (const float*)d_in[1];
  float* out = (float*)d_out;

  float* gm     = (float*)d_ws;                      // 2 MB
  float* dist   = gm + GM_F32;                       // 32 f32
  unsigned* cnt = (unsigned*)(dist + DB);            // 1 u32

  chamfer_main<<<NBLK, TPB, 0, stream>>>(x, y, gm, cnt);
  chamfer_combine<<<DB, 256, 0, stream>>>(gm, dist, cnt, out);
}

// Round 9
// 52.106 us; speedup vs baseline: 1.4193x; 1.0156x over previous
//
#include <hip/hip_runtime.h>

// MaxChamferDistance: x[16,4096,3], y[16,4096,3] f32 -> scalar f32
//
// Round-9: r8 closed the model: VALU ~15us (35%) + DS-broadcast ~20us (46%)
// + stage/tail ~= 44us. Broadcast ds_read_b128 pays the full ~12cy rate, so
// the q-stream DS term co-dominates. Fix: ownPT=16 (PH=8) halves DS to
// ~10us/CU while VALU stays ~14us.
//  - 512 blocks x 512 thr; block = (db, own-chunk 1024, other-group 1024).
//    Wave w streams private 128-pt slice (WSEG) from 16KB SoA LDS.
//  - per 4 other-pts: 4 ds_read_b128 + 8x(12 pk_fma + 4 min3).
//  - __launch_bounds__(512,4): VGPR<=128 -> 4 waves/SIMD, 2 blocks/CU
//    (LDS 49KB/block).
//  - cross-wave min in padded LDS; non-atomic group-major gm slab (2MB ws),
//    combine (32 blocks) + device-counter finale (r8-proven, deterministic).

#define BATCH   16
#define NPTS    4096
#define DB      (2 * BATCH)          // 32 (dir,batch)
#define TPB     512                  // 8 waves
#define WPB     8
#define OWNC    1024                 // own pts per block
#define PH      8                    // 16 own pts as 8 packed float2
#define OGROUPS 4
#define ORANGE  (NPTS / OGROUPS)     // 1024 other pts per block
#define WSEG    (ORANGE / WPB)       // 128 other pts per wave
#define OCHUNKS (NPTS / OWNC)        // 4
#define NBLK    (DB * OCHUNKS * OGROUPS)  // 512
#define GM_F32  (OGROUPS * DB * NPTS)     // 524288 floats = 2 MB
#define MPAD    1032                 // mins row stride (8-bank stagger)

typedef float v2f __attribute__((ext_vector_type(2)));

static __device__ __forceinline__ v2f fma2(v2f a, v2f b, v2f c) {
  return __builtin_elementwise_fma(a, b, c);
}
static __device__ __forceinline__ v2f splat2(float v) { return (v2f){v, v}; }

__global__ __launch_bounds__(TPB, 4) void chamfer_main(
    const float* __restrict__ x, const float* __restrict__ y,
    float* __restrict__ gm, unsigned* __restrict__ cnt) {
  __shared__ __align__(16) float lq[4][ORANGE];      // 16 KB SoA
  __shared__ float mins[WPB][MPAD];                  // 33 KB (padded rows)

  const int bid = blockIdx.x;
  if (bid == 0 && threadIdx.x == 0) *cnt = 0;        // reset for combine

  const int db = bid >> 4;             // 16 = OCHUNKS*OGROUPS blocks per db
  const int r  = bid & 15;
  const int c  = r >> 2;               // own chunk   [0,4)
  const int g  = r & 3;                // other group [0,4)
  const int dir = db >> 4;
  const int b   = db & 15;

  const float* own   = (dir == 0 ? x : y) + (size_t)b * NPTS * 3;
  const float* other = (dir == 0 ? y : x) + (size_t)b * NPTS * 3;
  const float* op    = other + (size_t)g * ORANGE * 3;

  // stage 1024 other pts, SoA, transformed: (-2p0,-2p1,-2p2,||p||^2)
  #pragma unroll
  for (int k = 0; k < 2; ++k) {
    const int i = threadIdx.x + k * TPB;             // [0,1024)
    float a0 = op[i * 3 + 0];
    float a1 = op[i * 3 + 1];
    float a2 = op[i * 3 + 2];
    lq[0][i] = -2.0f * a0;
    lq[1][i] = -2.0f * a1;
    lq[2][i] = -2.0f * a2;
    lq[3][i] = fmaf(a2, a2, fmaf(a1, a1, a0 * a0));
  }

  const int w    = __builtin_amdgcn_readfirstlane((int)(threadIdx.x >> 6));
  const int lane = threadIdx.x & 63;

  // 16 own points per lane as 8 packed float2 (same own pts for all waves)
  const int base = c * OWNC + lane;
  v2f x0p[PH], x1p[PH], x2p[PH], mnp[PH];
  #pragma unroll
  for (int j = 0; j < PH; ++j) {
    const int pa = base + (2 * j) * 64;
    const int pb = pa + 64;
    x0p[j] = (v2f){own[pa * 3 + 0], own[pb * 3 + 0]};
    x1p[j] = (v2f){own[pa * 3 + 1], own[pb * 3 + 1]};
    x2p[j] = (v2f){own[pa * 3 + 2], own[pb * 3 + 2]};
    mnp[j] = (v2f){1e30f, 1e30f};
  }
  __syncthreads();

  // stream this wave's private 128-pt slice (in-order ds_read_b128)
  const int mbase = w * WSEG;
  #pragma unroll 2
  for (int m = 0; m < WSEG; m += 4) {
    const float4 qx = *(const float4*)&lq[0][mbase + m];
    const float4 qy = *(const float4*)&lq[1][mbase + m];
    const float4 qz = *(const float4*)&lq[2][mbase + m];
    const float4 qw = *(const float4*)&lq[3][mbase + m];
    #pragma unroll
    for (int j = 0; j < PH; ++j) {
      v2f t0 = fma2(x0p[j], splat2(qx.x),
               fma2(x1p[j], splat2(qy.x),
               fma2(x2p[j], splat2(qz.x), splat2(qw.x))));
      v2f t1 = fma2(x0p[j], splat2(qx.y),
               fma2(x1p[j], splat2(qy.y),
               fma2(x2p[j], splat2(qz.y), splat2(qw.y))));
      v2f t2 = fma2(x0p[j], splat2(qx.z),
               fma2(x1p[j], splat2(qy.z),
               fma2(x2p[j], splat2(qz.z), splat2(qw.z))));
      v2f t3 = fma2(x0p[j], splat2(qx.w),
               fma2(x1p[j], splat2(qy.w),
               fma2(x2p[j], splat2(qz.w), splat2(qw.w))));
      float ux = fminf(fminf(t0.x, t1.x), t2.x);     // v_min3_f32
      float uy = fminf(fminf(t0.y, t1.y), t2.y);
      mnp[j].x = fminf(fminf(ux, t3.x), mnp[j].x);   // v_min3_f32
      mnp[j].y = fminf(fminf(uy, t3.y), mnp[j].y);
    }
  }

  // fold ||x||^2, publish per-wave mins
  #pragma unroll
  for (int j = 0; j < PH; ++j) {
    v2f sq = fma2(x2p[j], x2p[j], fma2(x1p[j], x1p[j], x0p[j] * x0p[j]));
    const int la = lane + (2 * j) * 64;
    mins[w][la]      = sq.x + mnp[j].x;
    mins[w][la + 64] = sq.y + mnp[j].y;
  }
  __syncthreads();

  // cross-wave min (fixed order) -> group-major slab, coalesced, no atomics
  #pragma unroll
  for (int k = 0; k < 2; ++k) {
    const int i = threadIdx.x + k * TPB;             // [0,1024)
    float v = mins[0][i];
    #pragma unroll
    for (int u = 1; u < WPB; ++u) v = fminf(v, mins[u][i]);
    gm[(size_t)g * (DB * NPTS) + (size_t)db * NPTS + c * OWNC + i] = v;
  }
}

// 32 blocks: min over 4 groups + per-db mean; last block folds max/mean.
__global__ __launch_bounds__(256) void chamfer_combine(
    const float* __restrict__ gm, float* __restrict__ dist,
    unsigned* __restrict__ cnt, float* __restrict__ out) {
  const int db = blockIdx.x;
  float s = 0.0f;
  for (int i = threadIdx.x; i < NPTS; i += 256) {
    const size_t o = (size_t)db * NPTS + i;
    float v0 = gm[o];
    float v1 = gm[o + (size_t)DB * NPTS];
    float v2 = gm[o + (size_t)2 * DB * NPTS];
    float v3 = gm[o + (size_t)3 * DB * NPTS];
    s += fminf(fminf(v0, v1), fminf(v2, v3));
  }
  #pragma unroll
  for (int off = 32; off > 0; off >>= 1) s += __shfl_down(s, off, 64);
  __shared__ float red[4];
  const int lane = threadIdx.x & 63, wid = threadIdx.x >> 6;
  if (lane == 0) red[wid] = s;
  __syncthreads();
  if (threadIdx.x == 0) {
    dist[db] = ((red[0] + red[1]) + (red[2] + red[3])) * (1.0f / (float)NPTS);
    __threadfence();
    unsigned old = __hip_atomic_fetch_add(cnt, 1u, __ATOMIC_ACQ_REL,
                                          __HIP_MEMORY_SCOPE_AGENT);
    if (old == DB - 1) {
      __threadfence();
      float acc = 0.0f;
      #pragma unroll
      for (int b = 0; b < BATCH; ++b) {
        float d0 = __uint_as_float(__hip_atomic_load(
            (const unsigned*)&dist[b], __ATOMIC_RELAXED,
            __HIP_MEMORY_SCOPE_AGENT));
        float d1 = __uint_as_float(__hip_atomic_load(
            (const unsigned*)&dist[b + BATCH], __ATOMIC_RELAXED,
            __HIP_MEMORY_SCOPE_AGENT));
        acc += fmaxf(d0, d1);
      }
      out[0] = acc * (1.0f / (float)BATCH);
    }
  }
}

extern "C" void kernel_launch(void* const* d_in, const int* in_sizes, int n_in,
                              void* d_out, int out_size, void* d_ws, size_t ws_size,
                              hipStream_t stream) {
  const float* x = (const float*)d_in[0];
  const float* y = (const float*)d_in[1];
  float* out = (float*)d_out;

  float* gm     = (float*)d_ws;                      // 2 MB
  float* dist   = gm + GM_F32;                       // 32 f32
  unsigned* cnt = (unsigned*)(dist + DB);            // 1 u32

  chamfer_main<<<NBLK, TPB, 0, stream>>>(x, y, gm, cnt);
  chamfer_combine<<<DB, 256, 0, stream>>>(gm, dist, cnt, out);
}

// Round 10
// 38.543 us; speedup vs baseline: 1.9188x; 1.3519x over previous
//
#include <hip/hip_runtime.h>

// MaxChamferDistance: x[16,4096,3], y[16,4096,3] f32 -> scalar f32
//
// Round-10: r9 proved we're at ~85% of the fp32-VALU exhaustive roofline
// (3 fma/pair = 24us pipe floor; observed 44us with ~30% dep-stall + ovh).
// Only way down: MFMA. K=11 bf16 hi/lo-split GEMM with fused min:
//   A(other pt m) k-chans = [yb_h(3), yb_l(3), yb_h(3), wh, wl], yb = -2y
//   B(own   pt n) k-chans = [xh(3),  xh(3),  xl(3),  1,  1 ]
//   => acc = ||y||^2 - 2<x,y> (+O(1e-4)); min over m = per-lane min3 of the
//   4 acc rows (C layout col=lane&15 <- B/own, row=(lane>>4)*4+reg <- A/other,
//   per m89-verified mapping); + ||x||^2 (exact f32) after the final min.
// Block = (db, 512 own pts): 8 waves x 4 n-tiles in regs; other cloud in 4
// chunks of 1024 staged as A-frags in LDS (512B/tile front half; K-slices
// 2,3 are a shared 16B zero line read broadcast by lanes 32-63).
// Per wave: 256 m-tiles x (1 ds_read_b128 + 4 MFMA + 8 min3).
// Deterministic: fixed-order mins/sums, non-atomic gm[32][64], 2 launches.

typedef __attribute__((ext_vector_type(8))) short bf16x8;
typedef __attribute__((ext_vector_type(4))) float f32x4;

#define BATCH   16
#define NPTS    4096
#define DB      (2 * BATCH)            // 32 (dir,batch)
#define TPB     512                    // 8 waves
#define NT      4                      // n-tiles (of 16) per wave
#define NPW     (NT * 16)              // 64 own pts per wave
#define NPB     (8 * NPW)              // 512 own pts per block
#define NBLOCKS (DB * (NPTS / NPB))    // 256
#define MCHUNK  1024                   // other pts per LDS chunk
#define MTILES  (MCHUNK / 16)          // 64
#define NCHUNKS (NPTS / MCHUNK)        // 4
#define LDSB    (16 + MTILES * 512)    // 16B zero line + 32KB frags

static __device__ __forceinline__ unsigned bf16rn(float f) {
  unsigned u = __float_as_uint(f);
  return (u + 0x7FFFu + ((u >> 16) & 1u)) >> 16;   // round-to-nearest-even
}
static __device__ __forceinline__ float bf2f(unsigned h) {
  return __uint_as_float(h << 16);
}
static __device__ __forceinline__ unsigned pk(unsigned lo, unsigned hi) {
  return (lo & 0xFFFFu) | (hi << 16);
}

__global__ __launch_bounds__(TPB) void chamfer_mfma(
    const float* __restrict__ x, const float* __restrict__ y,
    float* __restrict__ gm) {
  __shared__ __align__(16) unsigned char lds[LDSB];

  const int bid = blockIdx.x;
  const int db  = bid >> 3;            // 8 n-blocks per db
  const int nb  = bid & 7;
  const int dir = db >> 4;
  const int b   = db & 15;
  const float* own   = (dir == 0 ? x : y) + (size_t)b * NPTS * 3;
  const float* other = (dir == 0 ? y : x) + (size_t)b * NPTS * 3;

  const int tid = threadIdx.x;
  const int w   = tid >> 6;
  const int l   = tid & 63;
  const int col = l & 15;
  const int g   = l >> 4;              // K-slice group

  // 16B zero line at lds[0..16): lanes 32-63 broadcast-read it (K 16..31 = 0)
  if (tid < 4) *(unsigned*)&lds[tid * 4] = 0u;

  // resident B-frags: own points, K = [xh0,xh1,xh2, xh0,xh1,xh2, xl0,xl1,
  //                                    xl2, 1, 1, 0...]
  bf16x8 bfrag[NT];
  float  sq[NT], rmn[NT];
  #pragma unroll
  for (int nt = 0; nt < NT; ++nt) {
    const int n = nb * NPB + w * NPW + nt * 16 + col;
    float a0 = own[n * 3 + 0], a1 = own[n * 3 + 1], a2 = own[n * 3 + 2];
    sq[nt]  = fmaf(a2, a2, fmaf(a1, a1, a0 * a0));   // exact f32, added last
    rmn[nt] = 1e30f;
    unsigned h0 = bf16rn(a0), h1 = bf16rn(a1), h2 = bf16rn(a2);
    unsigned e0 = bf16rn(a0 - bf2f(h0));
    unsigned e1 = bf16rn(a1 - bf2f(h1));
    unsigned e2 = bf16rn(a2 - bf2f(h2));
    const unsigned ONE = 0x3F80u;                    // bf16(1.0)
    unsigned u0, u1, u2, u3;
    if (g == 0)      { u0 = pk(h0, h1); u1 = pk(h2, h0);
                       u2 = pk(h1, h2); u3 = pk(e0, e1); }   // K 0-7
    else if (g == 1) { u0 = pk(e2, ONE); u1 = pk(ONE, 0u);
                       u2 = 0u;          u3 = 0u; }          // K 8-15
    else             { u0 = u1 = u2 = u3 = 0u; }             // K 16-31
    union { unsigned uu[4]; bf16x8 v; } U;
    U.uu[0] = u0; U.uu[1] = u1; U.uu[2] = u2; U.uu[3] = u3;
    bfrag[nt] = U.v;
  }

  // A-frag read address: lanes 0-31 front halves, lanes 32-63 the zero line
  const int abase = (l < 32) ? (16 + l * 16) : 0;
  const int astep = (l < 32) ? 512 : 0;

  for (int mc = 0; mc < NCHUNKS; ++mc) {
    __syncthreads();                   // prev compute done before overwrite
    // stage 1024 other pts as A-frags: K = [yb_h0,yb_h1,yb_h2, yb_l0,yb_l1,
    //                                       yb_l2, yb_h0,yb_h1, yb_h2,wh,wl]
    #pragma unroll
    for (int k2 = 0; k2 < 2; ++k2) {
      const int p  = tid * 2 + k2;                   // [0,1024)
      const int pg = mc * MCHUNK + p;
      float y0 = other[pg * 3 + 0], y1 = other[pg * 3 + 1],
            y2 = other[pg * 3 + 2];
      float wv = fmaf(y2, y2, fmaf(y1, y1, y0 * y0));
      float z0 = -2.f * y0, z1 = -2.f * y1, z2 = -2.f * y2;
      unsigned h0 = bf16rn(z0), h1 = bf16rn(z1), h2 = bf16rn(z2);
      unsigned e0 = bf16rn(z0 - bf2f(h0));
      unsigned e1 = bf16rn(z1 - bf2f(h1));
      unsigned e2 = bf16rn(z2 - bf2f(h2));
      unsigned wh = bf16rn(wv), wl = bf16rn(wv - bf2f(wh));
      const int t = p >> 4, c = p & 15;
      *(uint4*)&lds[16 + t * 512 + c * 16] =
          make_uint4(pk(h0, h1), pk(h2, e0), pk(e1, e2), pk(h0, h1));
      *(uint4*)&lds[16 + t * 512 + (c + 16) * 16] =
          make_uint4(pk(h2, wh), pk(wl, 0u), 0u, 0u);
    }
    __syncthreads();

    // 64 m-tiles: 1 ds_read_b128 + 4 MFMA + 8 min3 each
    #pragma unroll 2
    for (int t = 0; t < MTILES; ++t) {
      const bf16x8 af = *(const bf16x8*)&lds[abase + t * astep];
      #pragma unroll
      for (int nt = 0; nt < NT; ++nt) {
        f32x4 z = {0.f, 0.f, 0.f, 0.f};
        f32x4 acc = __builtin_amdgcn_mfma_f32_16x16x32_bf16(
            af, bfrag[nt], z, 0, 0, 0);
        float mloc = fminf(fminf(acc[0], acc[1]), acc[2]);   // v_min3
        rmn[nt] = fminf(fminf(rmn[nt], acc[3]), mloc);       // v_min3
      }
    }
  }

  // epilogue: min across the 4 lane-groups (rows 4k), add sq_n, sum 64 n
  float s = 0.f;
  #pragma unroll
  for (int nt = 0; nt < NT; ++nt) {
    float v = rmn[nt];
    v = fminf(v, __shfl_xor(v, 16, 64));
    v = fminf(v, __shfl_xor(v, 32, 64));
    s += v + sq[nt];
  }
  #pragma unroll
  for (int m = 1; m <= 8; m <<= 1) s += __shfl_xor(s, m, 64);
  if (l == 0) gm[db * 64 + nb * 8 + w] = s;        // non-atomic, unique slot
}

// 1 block: fold gm[32][64] -> per-db mean -> per-batch max -> batch mean.
__global__ __launch_bounds__(1024) void chamfer_fin(
    const float* __restrict__ gm, float* __restrict__ out) {
  __shared__ float dls[DB];
  const int t = threadIdx.x;
  const int db = t >> 5, j = t & 31;
  float v = gm[db * 64 + j] + gm[db * 64 + j + 32];
  #pragma unroll
  for (int m = 1; m <= 16; m <<= 1) v += __shfl_xor(v, m, 64);
  if (j == 0) dls[db] = v * (1.0f / (float)NPTS);
  __syncthreads();
  if (t < BATCH) {
    float mx = fmaxf(dls[t], dls[t + BATCH]);
    #pragma unroll
    for (int m = 1; m <= 8; m <<= 1) mx += __shfl_xor(mx, m, 64);
    if (t == 0) out[0] = mx * (1.0f / (float)BATCH);
  }
}

extern "C" void kernel_launch(void* const* d_in, const int* in_sizes, int n_in,
                              void* d_out, int out_size, void* d_ws, size_t ws_size,
                              hipStream_t stream) {
  const float* x = (const float*)d_in[0];
  const float* y = (const float*)d_in[1];
  float* out = (float*)d_out;
  float* gm  = (float*)d_ws;                       // 32*64 f32 = 8 KB

  chamfer_mfma<<<NBLOCKS, TPB, 0, stream>>>(x, y, gm);
  chamfer_fin<<<1, 1024, 0, stream>>>(gm, out);
}

// Round 11
// 36.864 us; speedup vs baseline: 2.0062x; 1.0456x over previous
//
#include <hip/hip_runtime.h>

// MaxChamferDistance: x[16,4096,3], y[16,4096,3] f32 -> scalar f32
//
// Round-11: r10 (16x16x32 MFMA, 38.5us) was grid-starved (1 block/CU), paid
// 8x-redundant bf16 conversion, LDS bank conflicts, and wasted 21/32 K-chans.
// Now:
//  - 32x32x16 MFMA: 1024 pairs per 8cy (2.4x cheaper/pair), K=16 (11 used).
//  - prep kernel prestages A-frags (other pts) to global ws ONCE (4MB):
//    main kernel has NO LDS, NO barriers, loads A-frags 16B/lane (coalesced,
//    L1/L2-cached; each block's 64KB stream shared by 8 waves).
//  - 512 blocks x 512 thr = 4 waves/SIMD; block = (db, own-chunk 512,
//    m-half). Per wave: 64 tiles x [1 ld + 2 MFMA + 17 min-ops].
//  - per-point partial mins -> gm[2][32][4096] (1MB, non-atomic); r9-proven
//    combine + device-counter finale. All fixed-order => deterministic.
//  - ws < 5.25MB: falls back to r10's proven kernel verbatim.
// Numerics: A = [ybh(3), ybl(3), ybh(3), wh, wl, 0...], B = [xh(3), xh(3),
// xl(3), 1, 1, 0...] => acc = ||y||^2 - 2<x,y> + O(1e-4); ||x||^2 exact f32
// added after the min. C layout (m101): col=lane&31 (own), row from reg+half.

typedef __attribute__((ext_vector_type(8)))  short bf16x8;
typedef __attribute__((ext_vector_type(4)))  float f32x4;
typedef __attribute__((ext_vector_type(16))) float f32x16;

#define BATCH   16
#define NPTS    4096
#define DB      (2 * BATCH)            // 32 (dir,batch)
#define AF_U4   (DB * 128 * 64)        // 262144 uint4 = 4 MB
#define GM_F32  (2 * DB * NPTS)        // 262144 f32  = 1 MB

static __device__ __forceinline__ unsigned bf16rn(float f) {
  unsigned u = __float_as_uint(f);
  return (u + 0x7FFFu + ((u >> 16) & 1u)) >> 16;
}
static __device__ __forceinline__ float bf2f(unsigned h) {
  return __uint_as_float(h << 16);
}
static __device__ __forceinline__ unsigned pk(unsigned lo, unsigned hi) {
  return (lo & 0xFFFFu) | (hi << 16);
}

// ---- path A: prep (A-frag prestage, 512 blocks x 256) ---------------------
__global__ __launch_bounds__(256) void chamfer_prep(
    const float* __restrict__ x, const float* __restrict__ y,
    uint4* __restrict__ af, unsigned* __restrict__ cnt) {
  const int idx = blockIdx.x * 256 + threadIdx.x;  // [0, 131072)
  if (idx == 0) *cnt = 0;
  const int db = idx >> 12, m = idx & (NPTS - 1);
  const int dir = db >> 4, b = db & 15;
  const float* other = (dir == 0 ? y : x) + (size_t)b * NPTS * 3;
  float y0 = other[m * 3 + 0], y1 = other[m * 3 + 1], y2 = other[m * 3 + 2];
  float wv = fmaf(y2, y2, fmaf(y1, y1, y0 * y0));
  float z0 = -2.f * y0, z1 = -2.f * y1, z2 = -2.f * y2;
  unsigned h0 = bf16rn(z0), h1 = bf16rn(z1), h2 = bf16rn(z2);
  unsigned e0 = bf16rn(z0 - bf2f(h0));
  unsigned e1 = bf16rn(z1 - bf2f(h1));
  unsigned e2 = bf16rn(z2 - bf2f(h2));
  unsigned wh = bf16rn(wv), wl = bf16rn(wv - bf2f(wh));
  const int tile = m >> 5, row = m & 31;
  const size_t t0 = (size_t)(db * 128 + tile) * 64 + row;
  af[t0]      = make_uint4(pk(h0, h1), pk(h2, e0), pk(e1, e2), pk(h0, h1));
  af[t0 + 32] = make_uint4(pk(h2, wh), pk(wl, 0u), 0u, 0u);
}

// ---- path A: main (no LDS, no barriers; 512 blocks x 512) -----------------
__global__ __launch_bounds__(512, 4) void chamfer_mm(
    const float* __restrict__ x, const float* __restrict__ y,
    const uint4* __restrict__ af, float* __restrict__ gm) {
  const int bid = blockIdx.x;          // 512 = 32 db x 8 chunks x 2 m-halves
  const int db  = bid >> 4;
  const int r   = bid & 15;
  const int c   = r >> 1;              // own chunk [0,8)
  const int h   = r & 1;               // m-half
  const int dir = db >> 4, b = db & 15;
  const float* own = (dir == 0 ? x : y) + (size_t)b * NPTS * 3;

  const int tid = threadIdx.x, w = tid >> 6, l = tid & 63;
  const int col = l & 31, kh = l >> 5;
  const unsigned ONE = 0x3F80u;

  bf16x8 bfr[2];
  float sq[2], rmn[2];
  #pragma unroll
  for (int nt = 0; nt < 2; ++nt) {
    const int n = c * 512 + w * 64 + nt * 32 + col;
    float a0 = own[n * 3 + 0], a1 = own[n * 3 + 1], a2 = own[n * 3 + 2];
    sq[nt]  = fmaf(a2, a2, fmaf(a1, a1, a0 * a0));
    rmn[nt] = 1e30f;
    unsigned h0 = bf16rn(a0), h1 = bf16rn(a1), h2 = bf16rn(a2);
    unsigned e0 = bf16rn(a0 - bf2f(h0));
    unsigned e1 = bf16rn(a1 - bf2f(h1));
    unsigned e2 = bf16rn(a2 - bf2f(h2));
    union { unsigned uu[4]; bf16x8 v; } U;
    U.uu[0] = (kh == 0) ? pk(h0, h1) : pk(e2, ONE);
    U.uu[1] = (kh == 0) ? pk(h2, h0) : pk(ONE, 0u);
    U.uu[2] = (kh == 0) ? pk(h1, h2) : 0u;
    U.uu[3] = (kh == 0) ? pk(e0, e1) : 0u;
    bfr[nt] = U.v;
  }

  const uint4* qa = af + ((size_t)(db * 128 + h * 64) * 64 + l);
  const f32x16 z16 = {0.f, 0.f, 0.f, 0.f, 0.f, 0.f, 0.f, 0.f,
                      0.f, 0.f, 0.f, 0.f, 0.f, 0.f, 0.f, 0.f};

  #pragma unroll 2
  for (int mt = 0; mt < 64; ++mt) {
    union { uint4 u; bf16x8 v; } A;
    A.u = qa[(size_t)mt * 64];
    #pragma unroll
    for (int nt = 0; nt < 2; ++nt) {
      f32x16 acc = __builtin_amdgcn_mfma_f32_32x32x16_bf16(
          A.v, bfr[nt], z16, 0, 0, 0);
      float m0 = fminf(fminf(acc[0],  acc[1]),  acc[2]);    // v_min3 chains
      float m1 = fminf(fminf(acc[3],  acc[4]),  acc[5]);
      float m2 = fminf(fminf(acc[6],  acc[7]),  acc[8]);
      float m3 = fminf(fminf(acc[9],  acc[10]), acc[11]);
      float m4 = fminf(fminf(acc[12], acc[13]), acc[14]);
      float m5 = fminf(fminf(acc[15], m0), m1);
      float m6 = fminf(fminf(m2, m3), m4);
      rmn[nt] = fminf(fminf(m5, m6), rmn[nt]);
    }
  }

  // rows split across lane halves: fold lane^32, add exact ||x||^2, store
  #pragma unroll
  for (int nt = 0; nt < 2; ++nt) {
    float v = fminf(rmn[nt], __shfl_xor(rmn[nt], 32, 64));
    float sv = v + sq[nt];
    if (l < 32)
      gm[(size_t)(h * DB + db) * NPTS + c * 512 + w * 64 + nt * 32 + col] = sv;
  }
}

// ---- path A: combine (32 blocks) + counter-fused finale (r9-proven) -------
__global__ __launch_bounds__(256) void chamfer_combine(
    const float* __restrict__ gm, float* __restrict__ dist,
    unsigned* __restrict__ cnt, float* __restrict__ out) {
  const int db = blockIdx.x;
  const float* g0 = gm + (size_t)db * NPTS;
  const float* g1 = gm + (size_t)(DB + db) * NPTS;
  float s = 0.0f;
  for (int i = threadIdx.x; i < NPTS; i += 256)
    s += fminf(g0[i], g1[i]);
  #pragma unroll
  for (int off = 32; off > 0; off >>= 1) s += __shfl_down(s, off, 64);
  __shared__ float red[4];
  const int lane = threadIdx.x & 63, wid = threadIdx.x >> 6;
  if (lane == 0) red[wid] = s;
  __syncthreads();
  if (threadIdx.x == 0) {
    dist[db] = ((red[0] + red[1]) + (red[2] + red[3])) * (1.0f / (float)NPTS);
    __threadfence();
    unsigned old = __hip_atomic_fetch_add(cnt, 1u, __ATOMIC_ACQ_REL,
                                          __HIP_MEMORY_SCOPE_AGENT);
    if (old == DB - 1) {
      __threadfence();
      float acc = 0.0f;
      #pragma unroll
      for (int b = 0; b < BATCH; ++b) {
        float d0 = __uint_as_float(__hip_atomic_load(
            (const unsigned*)&dist[b], __ATOMIC_RELAXED,
            __HIP_MEMORY_SCOPE_AGENT));
        float d1 = __uint_as_float(__hip_atomic_load(
            (const unsigned*)&dist[b + BATCH], __ATOMIC_RELAXED,
            __HIP_MEMORY_SCOPE_AGENT));
        acc += fmaxf(d0, d1);
      }
      out[0] = acc * (1.0f / (float)BATCH);
    }
  }
}

// ---- path B: r10 fallback (proven 38.5us), used only if ws too small ------
#define TPB10    512
#define NT10     4
#define NPW10    (NT10 * 16)
#define NPB10    (8 * NPW10)
#define NBLK10   (DB * (NPTS / NPB10))
#define MCHUNK10 1024
#define MTILES10 (MCHUNK10 / 16)
#define LDSB10   (16 + MTILES10 * 512)

__global__ __launch_bounds__(TPB10) void chamfer_mfma10(
    const float* __restrict__ x, const float* __restrict__ y,
    float* __restrict__ gm) {
  __shared__ __align__(16) unsigned char lds[LDSB10];
  const int bid = blockIdx.x;
  const int db  = bid >> 3;
  const int nb  = bid & 7;
  const int dir = db >> 4;
  const int b   = db & 15;
  const float* own   = (dir == 0 ? x : y) + (size_t)b * NPTS * 3;
  const float* other = (dir == 0 ? y : x) + (size_t)b * NPTS * 3;
  const int tid = threadIdx.x, w = tid >> 6, l = tid & 63;
  const int col = l & 15, g = l >> 4;
  if (tid < 4) *(unsigned*)&lds[tid * 4] = 0u;
  bf16x8 bfrag[NT10];
  float  sq[NT10], rmn[NT10];
  #pragma unroll
  for (int nt = 0; nt < NT10; ++nt) {
    const int n = nb * NPB10 + w * NPW10 + nt * 16 + col;
    float a0 = own[n * 3 + 0], a1 = own[n * 3 + 1], a2 = own[n * 3 + 2];
    sq[nt]  = fmaf(a2, a2, fmaf(a1, a1, a0 * a0));
    rmn[nt] = 1e30f;
    unsigned h0 = bf16rn(a0), h1 = bf16rn(a1), h2 = bf16rn(a2);
    unsigned e0 = bf16rn(a0 - bf2f(h0));
    unsigned e1 = bf16rn(a1 - bf2f(h1));
    unsigned e2 = bf16rn(a2 - bf2f(h2));
    const unsigned ONE = 0x3F80u;
    unsigned u0, u1, u2, u3;
    if (g == 0)      { u0 = pk(h0, h1); u1 = pk(h2, h0);
                       u2 = pk(h1, h2); u3 = pk(e0, e1); }
    else if (g == 1) { u0 = pk(e2, ONE); u1 = pk(ONE, 0u); u2 = 0u; u3 = 0u; }
    else             { u0 = u1 = u2 = u3 = 0u; }
    union { unsigned uu[4]; bf16x8 v; } U;
    U.uu[0] = u0; U.uu[1] = u1; U.uu[2] = u2; U.uu[3] = u3;
    bfrag[nt] = U.v;
  }
  const int abase = (l < 32) ? (16 + l * 16) : 0;
  const int astep = (l < 32) ? 512 : 0;
  for (int mc = 0; mc < NPTS / MCHUNK10; ++mc) {
    __syncthreads();
    #pragma unroll
    for (int k2 = 0; k2 < 2; ++k2) {
      const int p  = tid * 2 + k2;
      const int pg = mc * MCHUNK10 + p;
      float y0 = other[pg * 3 + 0], y1 = other[pg * 3 + 1],
            y2 = other[pg * 3 + 2];
      float wv = fmaf(y2, y2, fmaf(y1, y1, y0 * y0));
      float z0 = -2.f * y0, z1 = -2.f * y1, z2 = -2.f * y2;
      unsigned h0 = bf16rn(z0), h1 = bf16rn(z1), h2 = bf16rn(z2);
      unsigned e0 = bf16rn(z0 - bf2f(h0));
      unsigned e1 = bf16rn(z1 - bf2f(h1));
      unsigned e2 = bf16rn(z2 - bf2f(h2));
      unsigned wh = bf16rn(wv), wl = bf16rn(wv - bf2f(wh));
      const int t = p >> 4, c = p & 15;
      *(uint4*)&lds[16 + t * 512 + c * 16] =
          make_uint4(pk(h0, h1), pk(h2, e0), pk(e1, e2), pk(h0, h1));
      *(uint4*)&lds[16 + t * 512 + (c + 16) * 16] =
          make_uint4(pk(h2, wh), pk(wl, 0u), 0u, 0u);
    }
    __syncthreads();
    #pragma unroll 2
    for (int t = 0; t < MTILES10; ++t) {
      const bf16x8 afv = *(const bf16x8*)&lds[abase + t * astep];
      #pragma unroll
      for (int nt = 0; nt < NT10; ++nt) {
        f32x4 z = {0.f, 0.f, 0.f, 0.f};
        f32x4 acc = __builtin_amdgcn_mfma_f32_16x16x32_bf16(
            afv, bfrag[nt], z, 0, 0, 0);
        float mloc = fminf(fminf(acc[0], acc[1]), acc[2]);
        rmn[nt] = fminf(fminf(rmn[nt], acc[3]), mloc);
      }
    }
  }
  float s = 0.f;
  #pragma unroll
  for (int nt = 0; nt < NT10; ++nt) {
    float v = rmn[nt];
    v = fminf(v, __shfl_xor(v, 16, 64));
    v = fminf(v, __shfl_xor(v, 32, 64));
    s += v + sq[nt];
  }
  #pragma unroll
  for (int m = 1; m <= 8; m <<= 1) s += __shfl_xor(s, m, 64);
  if (l == 0) gm[db * 64 + nb * 8 + w] = s;
}

__global__ __launch_bounds__(1024) void chamfer_fin10(
    const float* __restrict__ gm, float* __restrict__ out) {
  __shared__ float dls[DB];
  const int t = threadIdx.x;
  const int db = t >> 5, j = t & 31;
  float v = gm[db * 64 + j] + gm[db * 64 + j + 32];
  #pragma unroll
  for (int m = 1; m <= 16; m <<= 1) v += __shfl_xor(v, m, 64);
  if (j == 0) dls[db] = v * (1.0f / (float)NPTS);
  __syncthreads();
  if (t < BATCH) {
    float mx = fmaxf(dls[t], dls[t + BATCH]);
    #pragma unroll
    for (int m = 1; m <= 8; m <<= 1) mx += __shfl_xor(mx, m, 64);
    if (t == 0) out[0] = mx * (1.0f / (float)BATCH);
  }
}

extern "C" void kernel_launch(void* const* d_in, const int* in_sizes, int n_in,
                              void* d_out, int out_size, void* d_ws, size_t ws_size,
                              hipStream_t stream) {
  const float* x = (const float*)d_in[0];
  const float* y = (const float*)d_in[1];
  float* out = (float*)d_out;

  const size_t need = (size_t)AF_U4 * 16 + (size_t)GM_F32 * 4 + DB * 4 + 4;
  if (ws_size >= need) {
    uint4* af     = (uint4*)d_ws;                            // 4 MB
    float* gm     = (float*)((char*)d_ws + (size_t)AF_U4 * 16);   // 1 MB
    float* dist   = gm + GM_F32;                             // 32 f32
    unsigned* cnt = (unsigned*)(dist + DB);                  // 1 u32
    chamfer_prep<<<512, 256, 0, stream>>>(x, y, af, cnt);
    chamfer_mm<<<512, 512, 0, stream>>>(x, y, af, gm);
    chamfer_combine<<<DB, 256, 0, stream>>>(gm, dist, cnt, out);
  } else {
    float* gm = (float*)d_ws;                                // 8 KB
    chamfer_mfma10<<<NBLK10, TPB10, 0, stream>>>(x, y, gm);
    chamfer_fin10<<<1, 1024, 0, stream>>>(gm, out);
  }
}

// Round 12
// 29.814 us; speedup vs baseline: 2.4805x; 1.2365x over previous
//
#include <hip/hip_runtime.h>

// MaxChamferDistance: x[16,4096,3], y[16,4096,3] f32 -> scalar f32
//
// Round-12: r11's 3-launch prestage traded LDS for an L2 A-stream (8x reread,
// latency-exposed) plus an extra launch. Fused back:
//  - 2 launches: mm (512 blocks x 512 thr) + combine (32 blocks, counter-
//    fused finale, r9/r11-proven).
//  - block = (db, own-chunk 512, m-half 2048): converts its 2048 other pts
//    to 32x32x16 A-frags in 64KB LDS ONCE (1 barrier), then 64 tiles x
//    [1 ds_read_b128 (contiguous 1KB/wave, conflict-free) + 2 MFMA + min3
//    tree]. No prep kernel, no global A slab.
//  - numerics identical to r10/r11 (absmax 0 twice): A=[ybh(3),ybl(3),ybh(3),
//    wh,wl], B=[xh(3),xh(3),xl(3),1,1], exact-f32 ||x||^2 added post-min.
//  - mm block 0 zeroes cnt (stream-ordered before combine); gm[2][32][4096]
//    non-atomic; all reductions fixed-order => replay-deterministic.

typedef __attribute__((ext_vector_type(8)))  short bf16x8;
typedef __attribute__((ext_vector_type(16))) float f32x16;

#define BATCH   16
#define NPTS    4096
#define DB      (2 * BATCH)            // 32 (dir,batch)
#define GM_F32  (2 * DB * NPTS)        // 262144 f32 = 1 MB

static __device__ __forceinline__ unsigned bf16rn(float f) {
  unsigned u = __float_as_uint(f);
  return (u + 0x7FFFu + ((u >> 16) & 1u)) >> 16;   // round-to-nearest-even
}
static __device__ __forceinline__ float bf2f(unsigned h) {
  return __uint_as_float(h << 16);
}
static __device__ __forceinline__ unsigned pk(unsigned lo, unsigned hi) {
  return (lo & 0xFFFFu) | (hi << 16);
}

__global__ __launch_bounds__(512, 4) void chamfer_mm(
    const float* __restrict__ x, const float* __restrict__ y,
    float* __restrict__ gm, unsigned* __restrict__ cnt) {
  // 64 m-tiles x 64 uint4 (tile layout: [kh(2)][row(32)]) = 64 KB
  __shared__ __align__(16) uint4 afl[64 * 64];

  const int bid = blockIdx.x;          // 512 = 32 db x 8 own-chunks x 2 halves
  const int tid = threadIdx.x;
  if (bid == 0 && tid == 0) *cnt = 0;  // combine's counter (stream-ordered)

  const int db  = bid >> 4;
  const int r   = bid & 15;
  const int c   = r >> 1;              // own chunk [0,8)
  const int h   = r & 1;               // m-half
  const int dir = db >> 4, b = db & 15;
  const float* own   = (dir == 0 ? x : y) + (size_t)b * NPTS * 3;
  const float* other = (dir == 0 ? y : x) + (size_t)b * NPTS * 3;
  const float* mp    = other + (size_t)h * 2048 * 3;

  // ---- stage: convert 2048 other pts -> A-frags in LDS (4 pts/thread) ----
  #pragma unroll
  for (int k = 0; k < 4; ++k) {
    const int p = tid + k * 512;       // [0,2048)
    float y0 = mp[p * 3 + 0], y1 = mp[p * 3 + 1], y2 = mp[p * 3 + 2];
    float wv = fmaf(y2, y2, fmaf(y1, y1, y0 * y0));
    float z0 = -2.f * y0, z1 = -2.f * y1, z2 = -2.f * y2;
    unsigned h0 = bf16rn(z0), h1 = bf16rn(z1), h2 = bf16rn(z2);
    unsigned e0 = bf16rn(z0 - bf2f(h0));
    unsigned e1 = bf16rn(z1 - bf2f(h1));
    unsigned e2 = bf16rn(z2 - bf2f(h2));
    unsigned wh = bf16rn(wv), wl = bf16rn(wv - bf2f(wh));
    const int tile = p >> 5, row = p & 31;
    afl[tile * 64 + row]      =
        make_uint4(pk(h0, h1), pk(h2, e0), pk(e1, e2), pk(h0, h1)); // K0-7
    afl[tile * 64 + 32 + row] =
        make_uint4(pk(h2, wh), pk(wl, 0u), 0u, 0u);                 // K8-15
  }

  // ---- resident B-frags: 64 own pts per wave (2 n-tiles of 32) ----------
  const int w = tid >> 6, l = tid & 63;
  const int col = l & 31, kh = l >> 5;
  const unsigned ONE = 0x3F80u;
  bf16x8 bfr[2];
  float sq[2], rmn[2];
  #pragma unroll
  for (int nt = 0; nt < 2; ++nt) {
    const int n = c * 512 + w * 64 + nt * 32 + col;
    float a0 = own[n * 3 + 0], a1 = own[n * 3 + 1], a2 = own[n * 3 + 2];
    sq[nt]  = fmaf(a2, a2, fmaf(a1, a1, a0 * a0));   // exact f32, added last
    rmn[nt] = 1e30f;
    unsigned h0 = bf16rn(a0), h1 = bf16rn(a1), h2 = bf16rn(a2);
    unsigned e0 = bf16rn(a0 - bf2f(h0));
    unsigned e1 = bf16rn(a1 - bf2f(h1));
    unsigned e2 = bf16rn(a2 - bf2f(h2));
    union { unsigned uu[4]; bf16x8 v; } U;
    U.uu[0] = (kh == 0) ? pk(h0, h1) : pk(e2, ONE);
    U.uu[1] = (kh == 0) ? pk(h2, h0) : pk(ONE, 0u);
    U.uu[2] = (kh == 0) ? pk(h1, h2) : 0u;
    U.uu[3] = (kh == 0) ? pk(e0, e1) : 0u;
    bfr[nt] = U.v;
  }
  __syncthreads();

  // ---- main loop: 64 tiles x [1 ds_read_b128 + 2 MFMA + min3 tree] ------
  const int aoff = kh * 32 + col;      // lane's uint4 index within a tile
  const f32x16 z16 = {0.f, 0.f, 0.f, 0.f, 0.f, 0.f, 0.f, 0.f,
                      0.f, 0.f, 0.f, 0.f, 0.f, 0.f, 0.f, 0.f};
  #pragma unroll 4
  for (int mt = 0; mt < 64; ++mt) {
    union { uint4 u; bf16x8 v; } A;
    A.u = afl[mt * 64 + aoff];
    #pragma unroll
    for (int nt = 0; nt < 2; ++nt) {
      f32x16 acc = __builtin_amdgcn_mfma_f32_32x32x16_bf16(
          A.v, bfr[nt], z16, 0, 0, 0);
      float m0 = fminf(fminf(acc[0],  acc[1]),  acc[2]);   // v_min3 chains
      float m1 = fminf(fminf(acc[3],  acc[4]),  acc[5]);
      float m2 = fminf(fminf(acc[6],  acc[7]),  acc[8]);
      float m3 = fminf(fminf(acc[9],  acc[10]), acc[11]);
      float m4 = fminf(fminf(acc[12], acc[13]), acc[14]);
      float m5 = fminf(fminf(acc[15], m0), m1);
      float m6 = fminf(fminf(m2, m3), m4);
      rmn[nt] = fminf(fminf(m5, m6), rmn[nt]);
    }
  }

  // ---- epilogue: rows live in both lane halves -> fold lane^32 ----------
  #pragma unroll
  for (int nt = 0; nt < 2; ++nt) {
    float v = fminf(rmn[nt], __shfl_xor(rmn[nt], 32, 64));
    float sv = v + sq[nt];
    if (l < 32)
      gm[(size_t)(h * DB + db) * NPTS + c * 512 + w * 64 + nt * 32 + col] = sv;
  }
}

// 32 blocks: min over halves + per-db mean; last block folds max/mean -> out.
__global__ __launch_bounds__(256) void chamfer_combine(
    const float* __restrict__ gm, float* __restrict__ dist,
    unsigned* __restrict__ cnt, float* __restrict__ out) {
  const int db = blockIdx.x;
  const float* g0 = gm + (size_t)db * NPTS;
  const float* g1 = gm + (size_t)(DB + db) * NPTS;
  float s = 0.0f;
  for (int i = threadIdx.x; i < NPTS; i += 256)
    s += fminf(g0[i], g1[i]);
  #pragma unroll
  for (int off = 32; off > 0; off >>= 1) s += __shfl_down(s, off, 64);
  __shared__ float red[4];
  const int lane = threadIdx.x & 63, wid = threadIdx.x >> 6;
  if (lane == 0) red[wid] = s;
  __syncthreads();
  if (threadIdx.x == 0) {
    dist[db] = ((red[0] + red[1]) + (red[2] + red[3])) * (1.0f / (float)NPTS);
    __threadfence();
    unsigned old = __hip_atomic_fetch_add(cnt, 1u, __ATOMIC_ACQ_REL,
                                          __HIP_MEMORY_SCOPE_AGENT);
    if (old == DB - 1) {
      __threadfence();
      float acc = 0.0f;
      #pragma unroll
      for (int b = 0; b < BATCH; ++b) {
        float d0 = __uint_as_float(__hip_atomic_load(
            (const unsigned*)&dist[b], __ATOMIC_RELAXED,
            __HIP_MEMORY_SCOPE_AGENT));
        float d1 = __uint_as_float(__hip_atomic_load(
            (const unsigned*)&dist[b + BATCH], __ATOMIC_RELAXED,
            __HIP_MEMORY_SCOPE_AGENT));
        acc += fmaxf(d0, d1);
      }
      out[0] = acc * (1.0f / (float)BATCH);
    }
  }
}

extern "C" void kernel_launch(void* const* d_in, const int* in_sizes, int n_in,
                              void* d_out, int out_size, void* d_ws, size_t ws_size,
                              hipStream_t stream) {
  const float* x = (const float*)d_in[0];
  const float* y = (const float*)d_in[1];
  float* out = (float*)d_out;

  float* gm     = (float*)d_ws;                    // 1 MB
  float* dist   = gm + GM_F32;                     // 32 f32
  unsigned* cnt = (unsigned*)(dist + DB);          // 1 u32

  chamfer_mm<<<512, 512, 0, stream>>>(x, y, gm, cnt);
  chamfer_combine<<<DB, 256, 0, stream>>>(gm, dist, cnt, out);
}